// Round 1
// baseline (274.561 us; speedup 1.0000x reference)
//
#include <hip/hip_runtime.h>
#include <hip/hip_bf16.h>
#include <cstdint>
#include <math.h>

#define NB 4
#define NN 512
#define DH 128
#define NHEADS 8
#define NHID 16
#define SLOPE 0.2f

// Fused projection: g_l = h @ Wl, g_r = h @ Wr.
// Layer 0: h row computed on the fly from X @ W_in (Din=2).
__global__ __launch_bounds__(256) void proj_kernel(
    const float* __restrict__ h, const float* __restrict__ X,
    const float* __restrict__ Win,
    const float* __restrict__ Wl, const float* __restrict__ Wr,
    float* __restrict__ gl, float* __restrict__ gr)
{
    __shared__ float s_h[DH];
    const int bn = blockIdx.x;          // b*512 + n
    const int t  = threadIdx.x;

    if (t < DH) {
        if (X) {
            const float x0 = X[bn * 2 + 0];
            const float x1 = X[bn * 2 + 1];
            s_h[t] = x0 * Win[t] + x1 * Win[DH + t];
        } else {
            s_h[t] = h[(size_t)bn * DH + t];
        }
    }
    __syncthreads();

    const float* W = (t < DH) ? Wl : Wr;   // wave-uniform split (waves 0-1 vs 2-3)
    float*       g = (t < DH) ? gl : gr;
    const int d = t & (DH - 1);
    float acc = 0.f;
#pragma unroll 8
    for (int k = 0; k < DH; ++k) acc += s_h[k] * W[k * DH + d];  // coalesced column read
    g[(size_t)bn * DH + d] = acc;
}

// One block per (b,i). 512 threads.
// Phase A: thread j -> scores e[j][h] for all 8 heads (LDS stride 9 = conflict-free).
// Phase B: wave w -> softmax for head w (shuffle reduce over 64 lanes x 8 strided j).
// Phase C: thread (f = t&127, q = t>>7) -> partial aggregation over j-quarter q.
__global__ __launch_bounds__(512) void attn_kernel(
    const float* __restrict__ gl, const float* __restrict__ gr,
    const int* __restrict__ adj, const float* __restrict__ a_vec,
    float* __restrict__ h_out,
    const float* __restrict__ Wout, float* __restrict__ out)
{
    __shared__ float s_att[NN][9];                 // padded: stride 9 breaks bank conflicts
    __shared__ __align__(16) float s_gri[DH];
    __shared__ __align__(16) float s_a[NHID];
    __shared__ float s_part[4][DH];

    const int bi = blockIdx.x;     // b*512 + i
    const int b  = bi >> 9;
    const int i  = bi & (NN - 1);
    const int t  = threadIdx.x;

    if (t < DH)   s_gri[t] = gr[(size_t)bi * DH + t];
    if (t < NHID) s_a[t]   = a_vec[t];
    __syncthreads();

    // ---- Phase A: scores ----
    {
        const int j  = t;
        const int aj = adj[((size_t)b << 18) + ((size_t)i << 9) + j];
        if (aj == 0) {
#pragma unroll
            for (int hh = 0; hh < NHEADS; ++hh) s_att[j][hh] = -INFINITY;
        } else {
            const float4* glj4 = (const float4*)(gl + ((((size_t)b << 9) + j) << 7));
            const float4* gri4 = (const float4*)s_gri;
            const float4* a4   = (const float4*)s_a;
#pragma unroll
            for (int hh = 0; hh < NHEADS; ++hh) {
                float s = 0.f;
#pragma unroll
                for (int q = 0; q < 4; ++q) {
                    const float4 g  = glj4[hh * 4 + q];
                    const float4 r  = gri4[hh * 4 + q];
                    const float4 av = a4[q];
                    float v;
                    v = g.x + r.x; v = (v > 0.f) ? v : SLOPE * v; s += v * av.x;
                    v = g.y + r.y; v = (v > 0.f) ? v : SLOPE * v; s += v * av.y;
                    v = g.z + r.z; v = (v > 0.f) ? v : SLOPE * v; s += v * av.z;
                    v = g.w + r.w; v = (v > 0.f) ? v : SLOPE * v; s += v * av.w;
                }
                s_att[j][hh] = s;
            }
        }
    }
    __syncthreads();

    // ---- Phase B: per-head softmax over j (wave w == head w) ----
    {
        const int hh   = t >> 6;
        const int lane = t & 63;
        float m = -INFINITY;
#pragma unroll
        for (int k = 0; k < 8; ++k) m = fmaxf(m, s_att[lane + (k << 6)][hh]);
#pragma unroll
        for (int off = 32; off; off >>= 1) m = fmaxf(m, __shfl_xor(m, off));
        float ev[8];
        float sum = 0.f;
#pragma unroll
        for (int k = 0; k < 8; ++k) {
            const float e = expf(s_att[lane + (k << 6)][hh] - m);  // exp(-inf)=0 for masked
            ev[k] = e; sum += e;
        }
#pragma unroll
        for (int off = 32; off; off >>= 1) sum += __shfl_xor(sum, off);
        const float inv = 1.f / sum;
#pragma unroll
        for (int k = 0; k < 8; ++k) s_att[lane + (k << 6)][hh] = ev[k] * inv;
    }
    __syncthreads();

    // ---- Phase C: aggregate out[f] = sum_j att[j][h] * gr[b,j,f] ----
    {
        const int f  = t & (DH - 1);
        const int q  = t >> 7;
        const int hh = f >> 4;
        const float* grp = gr + ((size_t)b << 16) + f;   // gr[b,0,f]
        float acc = 0.f;
        const int j0 = q << 7;
#pragma unroll 4
        for (int j = j0; j < j0 + 128; ++j)
            acc += s_att[j][hh] * grp[(size_t)j << 7];   // coalesced 256B/wave
        s_part[q][f] = acc;
    }
    __syncthreads();

    if (t < DH) {
        const float r = s_part[0][t] + s_part[1][t] + s_part[2][t] + s_part[3][t];
        if (Wout) {
            s_part[0][t] = r * Wout[t];      // fused final h @ W_out
        } else {
            h_out[(size_t)bi * DH + t] = r;
        }
    }
    if (Wout) {                               // block-uniform branch
        __syncthreads();
        if (t < 64) {
            float v = s_part[0][t] + s_part[0][t + 64];
#pragma unroll
            for (int off = 32; off; off >>= 1) v += __shfl_xor(v, off);
            if (t == 0) out[bi] = v;
        }
    }
}

extern "C" void kernel_launch(void* const* d_in, const int* in_sizes, int n_in,
                              void* d_out, int out_size, void* d_ws, size_t ws_size,
                              hipStream_t stream) {
    const float* X    = (const float*)d_in[0];   // [4,512,2]
    const int*   adj  = (const int*)  d_in[1];   // [4,512,512]
    const float* Win  = (const float*)d_in[2];   // [2,128]
    const float* Wl   = (const float*)d_in[3];   // [3,128,128]
    const float* Wr   = (const float*)d_in[4];   // [3,128,128]
    const float* Aa   = (const float*)d_in[5];   // [3,16]
    const float* Wout = (const float*)d_in[6];   // [128,1]
    float* out = (float*)d_out;                  // [4,512,1] fp32

    float* ws = (float*)d_ws;
    float* h  = ws;                // 262144 floats (1 MB)
    float* gl = ws + 262144;       // 1 MB
    float* gr = ws + 524288;       // 1 MB

    const int BN = NB * NN;        // 2048

    for (int l = 0; l < 3; ++l) {
        proj_kernel<<<BN, 256, 0, stream>>>(
            h, (l == 0) ? X : nullptr, Win,
            Wl + (size_t)l * DH * DH, Wr + (size_t)l * DH * DH, gl, gr);
        const bool last = (l == 2);
        attn_kernel<<<BN, 512, 0, stream>>>(
            gl, gr, adj, Aa + l * NHID, h,
            last ? Wout : nullptr, out);
    }
}

// Round 2
// 262.846 us; speedup vs baseline: 1.0446x; 1.0446x over previous
//
#include <hip/hip_runtime.h>
#include <hip/hip_bf16.h>
#include <cstdint>
#include <math.h>

#define NB 4
#define NN 512
#define DH 128
#define NHEADS 8
#define NHID 16
#define SLOPE 0.2f
#define TI 4
#define SATT_STRIDE 516   // 512+4: consecutive head-rows start on different LDS banks

// Projection: 8 node-rows per block, 256 threads (t<128 -> gl, t>=128 -> gr).
// Each W element loaded once feeds 8 FMAs (register reuse across rows).
__global__ __launch_bounds__(256) void proj_kernel(
    const float* __restrict__ h, const float* __restrict__ X,
    const float* __restrict__ Win,
    const float* __restrict__ Wl, const float* __restrict__ Wr,
    float* __restrict__ gl, float* __restrict__ gr)
{
    __shared__ __align__(16) float s_h[8][DH];
    const int bn0 = blockIdx.x * 8;
    const int t = threadIdx.x;

    if (X) {
        if (t < DH) {
            const float w0 = Win[t], w1 = Win[DH + t];
#pragma unroll
            for (int r = 0; r < 8; ++r) {
                const float x0 = X[(bn0 + r) * 2 + 0];   // uniform scalar loads
                const float x1 = X[(bn0 + r) * 2 + 1];
                s_h[r][t] = x0 * w0 + x1 * w1;
            }
        }
    } else {
        for (int idx = t; idx < 8 * DH; idx += 256)
            s_h[idx >> 7][idx & 127] = h[(size_t)bn0 * DH + idx];
    }
    __syncthreads();

    const float* W = (t < DH) ? Wl : Wr;   // wave-uniform split
    float*       g = (t < DH) ? gl : gr;
    const int f = t & 127;
    float acc[8] = {};
    for (int k = 0; k < DH; k += 4) {
        const float w0 = W[(k + 0) * DH + f];
        const float w1 = W[(k + 1) * DH + f];
        const float w2 = W[(k + 2) * DH + f];
        const float w3 = W[(k + 3) * DH + f];
#pragma unroll
        for (int r = 0; r < 8; ++r) {
            const float4 hv = *(const float4*)&s_h[r][k];  // broadcast
            acc[r] += hv.x * w0 + hv.y * w1 + hv.z * w2 + hv.w * w3;
        }
    }
#pragma unroll
    for (int r = 0; r < 8; ++r)
        g[((size_t)bn0 + r) * DH + f] = acc[r];
}

// One block per (b, 4 query rows). 512 threads, 8 waves.
// A: thread j computes scores for 4 rows x 8 heads (gl row reused x4 in regs).
// B: wave w -> softmax for 4 (ti,head) pairs.
// C: thread (f0=(t&31)*4, q=t>>5) aggregates 32 j with float4 gr loads,
//    block-reduce via LDS atomicAdd.
__global__ __launch_bounds__(512) void attn_kernel(
    const float* __restrict__ gl, const float* __restrict__ gr,
    const int* __restrict__ adj, const float* __restrict__ a_vec,
    float* __restrict__ h_out,
    const float* __restrict__ Wout, float* __restrict__ out)
{
    __shared__ float s_att[TI * NHEADS * SATT_STRIDE];   // 66048 B
    __shared__ __align__(16) float s_gri[TI * DH];       // 2 KB
    __shared__ float s_out[TI * DH];                     // 2 KB
    __shared__ __align__(16) float s_a[NHID];

    const int blk = blockIdx.x;          // 0..511
    const int b   = blk >> 7;            // 128 blocks per batch
    const int i0  = (blk & 127) * TI;
    const int t   = threadIdx.x;

    {   // stage gr rows for the 4 queries + a + zero the output accumulator
        const int ti = t >> 7, f = t & 127;
        s_gri[ti * DH + f] = gr[((size_t)(b * NN + i0 + ti)) * DH + f];
        s_out[t] = 0.f;
        if (t < NHID) s_a[t] = a_vec[t];
    }
    __syncthreads();

    // ---- Phase A: scores ----
    {
        const int j = t;
        int amask[TI];
#pragma unroll
        for (int ti = 0; ti < TI; ++ti)
            amask[ti] = adj[((size_t)b << 18) + ((size_t)(i0 + ti) << 9) + j];
        const float4* glj = (const float4*)(gl + ((size_t)(b * NN + j)) * DH);
        const float4* a4  = (const float4*)s_a;
#pragma unroll
        for (int hh = 0; hh < NHEADS; ++hh) {
            float4 G[4];
#pragma unroll
            for (int q = 0; q < 4; ++q) G[q] = glj[hh * 4 + q];
#pragma unroll
            for (int ti = 0; ti < TI; ++ti) {
                const float4* r4 = (const float4*)(s_gri + ti * DH + hh * NHID);
                float s = 0.f;
#pragma unroll
                for (int q = 0; q < 4; ++q) {
                    const float4 g = G[q], r = r4[q], av = a4[q];
                    float v;
                    v = g.x + r.x; v = fmaxf(v, SLOPE * v); s += v * av.x;
                    v = g.y + r.y; v = fmaxf(v, SLOPE * v); s += v * av.y;
                    v = g.z + r.z; v = fmaxf(v, SLOPE * v); s += v * av.z;
                    v = g.w + r.w; v = fmaxf(v, SLOPE * v); s += v * av.w;
                }
                s_att[(ti * NHEADS + hh) * SATT_STRIDE + j] = amask[ti] ? s : -INFINITY;
            }
        }
    }
    __syncthreads();

    // ---- Phase B: softmax over j; 32 (ti,head) rows, 4 per wave ----
    {
        const int wv = t >> 6, lane = t & 63;
#pragma unroll
        for (int p = 0; p < 4; ++p) {
            float* row = s_att + (wv * 4 + p) * SATT_STRIDE;
            float e[8];
            float m = -INFINITY;
#pragma unroll
            for (int k = 0; k < 8; ++k) { e[k] = row[lane + (k << 6)]; m = fmaxf(m, e[k]); }
#pragma unroll
            for (int off = 32; off; off >>= 1) m = fmaxf(m, __shfl_xor(m, off));
            float sum = 0.f;
#pragma unroll
            for (int k = 0; k < 8; ++k) { e[k] = __expf(e[k] - m); sum += e[k]; }
#pragma unroll
            for (int off = 32; off; off >>= 1) sum += __shfl_xor(sum, off);
            const float inv = 1.f / sum;
#pragma unroll
            for (int k = 0; k < 8; ++k) row[lane + (k << 6)] = e[k] * inv;
        }
    }
    __syncthreads();

    // ---- Phase C: out[ti][f] = sum_j att[ti][h(f)][j] * gr[b,j,f] ----
    {
        const int f0 = (t & 31) << 2;        // 4 consecutive f per thread
        const int hh = f0 >> 4;
        const int q  = t >> 5;               // j-group 0..15 (32 j each)
        const float* gp   = gr + ((size_t)(b * NN + q * 32)) * DH + f0;
        const float* arow = s_att + hh * SATT_STRIDE + q * 32;
        float4 acc[TI] = {};
#pragma unroll 4
        for (int jj = 0; jj < 32; ++jj) {
            const float4 g = *(const float4*)(gp + (size_t)jj * DH);  // 16B/lane coalesced
#pragma unroll
            for (int ti = 0; ti < TI; ++ti) {
                const float a = arow[ti * (NHEADS * SATT_STRIDE) + jj];  // broadcast
                acc[ti].x += a * g.x; acc[ti].y += a * g.y;
                acc[ti].z += a * g.z; acc[ti].w += a * g.w;
            }
        }
#pragma unroll
        for (int ti = 0; ti < TI; ++ti) {
            atomicAdd(&s_out[ti * DH + f0 + 0], acc[ti].x);
            atomicAdd(&s_out[ti * DH + f0 + 1], acc[ti].y);
            atomicAdd(&s_out[ti * DH + f0 + 2], acc[ti].z);
            atomicAdd(&s_out[ti * DH + f0 + 3], acc[ti].w);
        }
    }
    __syncthreads();

    if (Wout) {                              // fused final h @ W_out
        if (t < 256) {
            const int ti = t >> 6, lane = t & 63;
            float v = s_out[ti * DH + lane]      * Wout[lane]
                    + s_out[ti * DH + lane + 64] * Wout[lane + 64];
#pragma unroll
            for (int off = 32; off; off >>= 1) v += __shfl_xor(v, off);
            if (lane == 0) out[b * NN + i0 + ti] = v;
        }
    } else {
        const int ti = t >> 7, f = t & 127;
        h_out[((size_t)(b * NN + i0 + ti)) * DH + f] = s_out[ti * DH + f];
    }
}

extern "C" void kernel_launch(void* const* d_in, const int* in_sizes, int n_in,
                              void* d_out, int out_size, void* d_ws, size_t ws_size,
                              hipStream_t stream) {
    const float* X    = (const float*)d_in[0];   // [4,512,2]
    const int*   adj  = (const int*)  d_in[1];   // [4,512,512]
    const float* Win  = (const float*)d_in[2];   // [2,128]
    const float* Wl   = (const float*)d_in[3];   // [3,128,128]
    const float* Wr   = (const float*)d_in[4];   // [3,128,128]
    const float* Aa   = (const float*)d_in[5];   // [3,16]
    const float* Wout = (const float*)d_in[6];   // [128,1]
    float* out = (float*)d_out;                  // [4,512] fp32

    float* ws = (float*)d_ws;
    float* h  = ws;                // 1 MB
    float* gl = ws + 262144;       // 1 MB
    float* gr = ws + 524288;       // 1 MB

    for (int l = 0; l < 3; ++l) {
        proj_kernel<<<NB * NN / 8, 256, 0, stream>>>(
            h, (l == 0) ? X : nullptr, Win,
            Wl + (size_t)l * DH * DH, Wr + (size_t)l * DH * DH, gl, gr);
        const bool last = (l == 2);
        attn_kernel<<<NB * NN / TI, 512, 0, stream>>>(
            gl, gr, adj, Aa + l * NHID, h,
            last ? Wout : nullptr, out);
    }
}